// Round 19
// baseline (145.544 us; speedup 1.0000x reference)
//
#include <hip/hip_runtime.h>

#define BATCH 8
#define SEQ   8192
#define NH    16
#define DP    64
#define ROWF  (NH*DP)        // 1024 floats = 4KB per t (all heads)
#define HGRP  4              // heads per block
#define NTHR  512            // 8 waves = 4 heads x 2 n-halves
#define KT    32             // t per k-tile = one mfma K-depth
#define RS    260            // dword row-stride: 260 mod 32 = 4 -> fragment reads
                             // land kg-groups on disjoint 16-bank halves (2-way =
                             // free, m136). RS=257 gave 4-way = 7.6M conflicts (r18).

typedef __attribute__((ext_vector_type(8))) short bf16x8;
typedef __attribute__((ext_vector_type(4))) float f32x4;

// round-to-nearest-even f32->bf16 pair pack: lo -> low 16 bits (even t = lower k)
static __device__ __forceinline__ unsigned pk2(float lo, float hi) {
    unsigned a = __builtin_bit_cast(unsigned, lo);
    unsigned b = __builtin_bit_cast(unsigned, hi);
    a = (a + 0x7FFFu + ((a >> 16) & 1u)) >> 16;
    b = (b + 0x7FFFu + ((b >> 16) & 1u)) & 0xFFFF0000u;
    return (a & 0xFFFFu) | b;
}

// ---------------------------------------------------------------------------
// k_partial (MFMA, r18 structure + conflict fix + LDS double-buffer):
// per (b,h,chunk): C[64p][64n] = sum_t (w*X)[t][p] * B[t][n]  (GEMM, K=t).
// r18 landed 155us (from 205 scalar); its residue was 4-way LDS read
// conflicts (RS=257) and 3 barriers + full lgkm drain per k-tile on a single
// buffer. This round: RS=260 (2-way = free) and XL/BL[2] double-buffer with
// ONE barrier per k-tile: compute(buf) overlaps cwrite(buf^1).
// ---------------------------------------------------------------------------
template<int NBLK>
__global__ __launch_bounds__(NTHR)
void k_partial(const float* __restrict__ Xg, const float* __restrict__ Ag,
               const float* __restrict__ Bg, float* __restrict__ part,
               float* __restrict__ blockA)
{
    constexpr int TB  = SEQ / NBLK;   // 256 (NBLK=32)
    constexpr int Q   = TB / 64;      // 4
    constexpr int NKT = TB / KT;      // 8

    __shared__ unsigned XL[2][16][RS];   // 2 x 16 t-pairs x 256(+pad) rows, w*X bf16x2
    __shared__ unsigned BL[2][16][RS];   // same for B  (total ~66.6 KB)
    __shared__ float    WT[HGRP][TB];    // per-head weights for this chunk

    const int gid  = blockIdx.x;            // b*(4*NBLK) + hg*NBLK + blk
    const int blk  = gid % NBLK;
    const int hg   = (gid / NBLK) & 3;
    const int b    = gid / (4 * NBLK);
    const int tid  = threadIdx.x;
    const int w    = tid >> 6;              // 0..7
    const int lane = tid & 63;
    const int hloc = w >> 1;                // head within group
    const int nh   = w & 1;                 // n-half
    const int h    = hg * HGRP + hloc;
    const int t0   = blk * TB;

    // ---- per-wave scan of A column h (redundant across the 2 waves/head) ----
    float c[Q];
    {
        const size_t abase = ((size_t)(b * SEQ + t0 + lane * Q)) * NH + h;
        float run = 0.f;
        #pragma unroll
        for (int k = 0; k < Q; ++k) { run += Ag[abase + (size_t)k * NH]; c[k] = run; }
    }
    float tsum = c[Q - 1], s = tsum;
    #pragma unroll
    for (int d = 1; d < 64; d <<= 1) {
        float o = __shfl_up(s, d, 64);
        if (lane >= d) s += o;
    }
    const float total = __shfl(s, 63, 64);
    const float excl  = s - tsum;
    if (nh == 0) {
        #pragma unroll
        for (int k = 0; k < Q; ++k)
            WT[hloc][lane * Q + k] = __expf(total - (excl + c[k]));
        if (lane == 63) blockA[(size_t)(b * NH + h) * NBLK + blk] = total;
    }

    // ---- accumulators: 4 m-tiles x 2 n-tiles of 16x16 ----
    f32x4 acc[4][2];
    #pragma unroll
    for (int mi = 0; mi < 4; ++mi)
        #pragma unroll
        for (int ni = 0; ni < 2; ++ni) acc[mi][ni] = (f32x4){0.f, 0.f, 0.f, 0.f};

    // staging geometry: one wave-load = one t-row of the 4-head slice (1KB)
    const int hl = lane >> 4;                // head this lane stages
    const int p4 = (lane & 15) * 4;          // 4 consecutive p
    const size_t gbase = (size_t)(b * SEQ + t0) * ROWF + hg * (HGRP * DP) + hl * DP + p4;

    auto issue = [&](int k, float4* lx, float4* lb) {
        if (k >= NKT) return;
        const size_t tb = gbase + (size_t)(k * KT + w * 4) * ROWF;
        #pragma unroll
        for (int i = 0; i < 4; ++i) {
            lx[i] = *(const float4*)(Xg + tb + (size_t)i * ROWF);
            lb[i] = *(const float4*)(Bg + tb + (size_t)i * ROWF);
        }
    };
    auto cwrite = [&](int k, int buf, const float4* lx, const float4* lb) {
        const int tIn = k * KT + w * 4;            // within-chunk t of lx[0]
        #pragma unroll
        for (int q = 0; q < 2; ++q) {
            const float w0 = WT[hl][tIn + 2 * q];
            const float w1 = WT[hl][tIn + 2 * q + 1];
            const int   tp = w * 2 + q;            // t-pair slot in tile (0..15)
            const float* x0 = (const float*)&lx[2 * q];
            const float* x1 = (const float*)&lx[2 * q + 1];
            const float* b0 = (const float*)&lb[2 * q];
            const float* b1 = (const float*)&lb[2 * q + 1];
            #pragma unroll
            for (int pp = 0; pp < 4; ++pp) {
                XL[buf][tp][hl * 64 + p4 + pp] = pk2(x0[pp] * w0, x1[pp] * w1);
                BL[buf][tp][hl * 64 + p4 + pp] = pk2(b0[pp], b1[pp]);
            }
        }
    };
    auto compute = [&](int buf) {
        const int r  = lane & 15;
        const int kg = lane >> 4;
        uint4 af[4], bf[2];
        #pragma unroll
        for (int mi = 0; mi < 4; ++mi) {
            const int row = hloc * 64 + mi * 16 + r;
            af[mi].x = XL[buf][kg * 4 + 0][row];
            af[mi].y = XL[buf][kg * 4 + 1][row];
            af[mi].z = XL[buf][kg * 4 + 2][row];
            af[mi].w = XL[buf][kg * 4 + 3][row];
        }
        #pragma unroll
        for (int ni = 0; ni < 2; ++ni) {
            const int row = hloc * 64 + nh * 32 + ni * 16 + r;
            bf[ni].x = BL[buf][kg * 4 + 0][row];
            bf[ni].y = BL[buf][kg * 4 + 1][row];
            bf[ni].z = BL[buf][kg * 4 + 2][row];
            bf[ni].w = BL[buf][kg * 4 + 3][row];
        }
        #pragma unroll
        for (int mi = 0; mi < 4; ++mi) {
            const bf16x8 a = __builtin_bit_cast(bf16x8, af[mi]);
            #pragma unroll
            for (int ni = 0; ni < 2; ++ni) {
                const bf16x8 bb = __builtin_bit_cast(bf16x8, bf[ni]);
                acc[mi][ni] = __builtin_amdgcn_mfma_f32_16x16x32_bf16(
                                  a, bb, acc[mi][ni], 0, 0, 0);
            }
        }
    };

    // ---- pipeline: 2 reg-sets, 2 LDS buffers, ONE barrier per k-tile ----
    float4 sx0[4], sb0[4], sx1[4], sb1[4];
    issue(0, sx0, sb0);
    issue(1, sx1, sb1);
    __syncthreads();                         // WT (and scan) visible

    cwrite(0, 0, sx0, sb0);                  // waits set0's global loads
    issue(2, sx0, sb0);
    asm volatile("s_waitcnt lgkmcnt(0)" ::: "memory");
    __builtin_amdgcn_s_barrier();            // buf0 = tile 0 ready
    __builtin_amdgcn_sched_barrier(0);

    #pragma unroll 1
    for (int k = 0; k < NKT; k += 2) {
        // phase A: cwrite tile k+1 -> buf1 (overlaps) ; compute tile k from buf0
        if (k + 1 < NKT) { cwrite(k + 1, 1, sx1, sb1); issue(k + 3, sx1, sb1); }
        compute(0);
        asm volatile("s_waitcnt lgkmcnt(0)" ::: "memory");
        __builtin_amdgcn_s_barrier();        // buf1 ready; buf0 reads done
        __builtin_amdgcn_sched_barrier(0);

        // phase B: cwrite tile k+2 -> buf0 ; compute tile k+1 from buf1
        if (k + 2 < NKT) { cwrite(k + 2, 0, sx0, sb0); issue(k + 4, sx0, sb0); }
        if (k + 1 < NKT) compute(1);
        asm volatile("s_waitcnt lgkmcnt(0)" ::: "memory");
        __builtin_amdgcn_s_barrier();        // buf0 ready; buf1 reads done
        __builtin_amdgcn_sched_barrier(0);
    }

    // ---- epilogue: C/D layout (m89): col = lane&15, row = (lane>>4)*4 + reg ----
    float* dst = part + ((size_t)(b * NH + h) * NBLK + blk) * 4096;
    {
        const int r  = lane & 15;
        const int cg = lane >> 4;
        #pragma unroll
        for (int mi = 0; mi < 4; ++mi)
            #pragma unroll
            for (int ni = 0; ni < 2; ++ni)
                #pragma unroll
                for (int rr = 0; rr < 4; ++rr)
                    dst[(mi * 16 + cg * 4 + rr) * 64 + nh * 32 + ni * 16 + r] =
                        acc[mi][ni][rr];
    }
}

// ---------------------------------------------------------------------------
// k_scales: suffix-exp over chunk totals, per (b,h)
// ---------------------------------------------------------------------------
__global__ void k_scales(const float* __restrict__ blockA, float* __restrict__ scale,
                         int nblk)
{
    const int bh = blockIdx.x * blockDim.x + threadIdx.x;
    if (bh < BATCH * NH) {
        float run = 0.f;
        for (int c2 = nblk - 1; c2 >= 0; --c2) {
            scale[bh * nblk + c2] = __expf(run);
            run += blockA[bh * nblk + c2];
        }
    }
}

// ---------------------------------------------------------------------------
// k_combine: out[bh,p,n] = sum_c scale[bh,c] * part[bh,c,p,n]
// ---------------------------------------------------------------------------
__global__ __launch_bounds__(256)
void k_combine(const float* __restrict__ part, const float* __restrict__ scale,
               float* __restrict__ out, int nblk)
{
    const int idx = blockIdx.x * 256 + threadIdx.x;   // 0..524287
    const int bh  = idx >> 12;
    const int e   = idx & 4095;
    float r = 0.f;
    for (int q = 0; q < nblk; ++q)
        r += scale[bh * nblk + q] * part[((size_t)bh * nblk + q) * 4096 + e];
    out[idx] = r;
}

// ---------------------------------------------------------------------------
extern "C" void kernel_launch(void* const* d_in, const int* in_sizes, int n_in,
                              void* d_out, int out_size, void* d_ws, size_t ws_size,
                              hipStream_t stream)
{
    const float* X = (const float*)d_in[0];
    const float* A = (const float*)d_in[1];
    const float* B = (const float*)d_in[2];
    float* out     = (float*)d_out;

    const size_t need32 = ((size_t)BATCH * NH * 32 * 4096 + 2ull * BATCH * NH * 32) * 4;
    const int nblk = (ws_size >= need32) ? 32 : 16;

    float* part   = (float*)d_ws;
    float* blockA = part + (size_t)BATCH * NH * nblk * 4096;
    float* scale  = blockA + (size_t)BATCH * NH * nblk;

    if (nblk == 32)
        hipLaunchKernelGGL((k_partial<32>), dim3(BATCH * 4 * 32), dim3(NTHR), 0, stream,
                           X, A, B, part, blockA);
    else
        hipLaunchKernelGGL((k_partial<16>), dim3(BATCH * 4 * 16), dim3(NTHR), 0, stream,
                           X, A, B, part, blockA);

    hipLaunchKernelGGL(k_scales, dim3(1), dim3(128), 0, stream, blockA, scale, nblk);
    hipLaunchKernelGGL(k_combine, dim3((BATCH * NH * 4096) / 256), dim3(256), 0, stream,
                       part, scale, out, nblk);
}

// Round 20
// 143.904 us; speedup vs baseline: 1.0114x; 1.0114x over previous
//
#include <hip/hip_runtime.h>

#define BATCH 8
#define SEQ   8192
#define NH    16
#define DP    64
#define ROWF  (NH*DP)        // 1024 floats = 4KB per t (all heads)
#define HGRP  4              // heads per block
#define NTHR  512            // 8 waves = 4 heads x 2 n-halves
#define KT    32             // t per k-tile = one mfma K-depth
#define RS    260            // dword row-stride (2-way bank alias = free; r19)

typedef __attribute__((ext_vector_type(8))) short bf16x8;
typedef __attribute__((ext_vector_type(4))) float f32x4;

// round-to-nearest-even f32->bf16 pair pack: lo -> low 16 bits (even t = lower k)
static __device__ __forceinline__ unsigned pk2(float lo, float hi) {
    unsigned a = __builtin_bit_cast(unsigned, lo);
    unsigned b = __builtin_bit_cast(unsigned, hi);
    a = (a + 0x7FFFu + ((a >> 16) & 1u)) >> 16;
    b = (b + 0x7FFFu + ((b >> 16) & 1u)) & 0xFFFF0000u;
    return (a & 0xFFFFu) | b;
}

// ---------------------------------------------------------------------------
// k_partial (MFMA): per (b,h,chunk): C[64p][64n] = sum_t (w*X)[t][p]*B[t][n].
// r19 residue: phases ~11.8K cyc vs ~3K compute, all ports idle -> cwrite's
// vmcnt wait (2-phase lead insufficient under loaded HBM latency). r20:
// 3-regset fully-unrolled pipeline (3-phase lead, cwrite never waits) +
// ds_write_b128 packed LDS writes (16 b32 -> 4 b128 per lane per tile).
// ---------------------------------------------------------------------------
template<int NBLK>
__global__ __launch_bounds__(NTHR)
void k_partial(const float* __restrict__ Xg, const float* __restrict__ Ag,
               const float* __restrict__ Bg, float* __restrict__ part,
               float* __restrict__ blockA)
{
    constexpr int TB  = SEQ / NBLK;   // 256 (NBLK=32)
    constexpr int Q   = TB / 64;
    constexpr int NKT = TB / KT;      // 8 (NBLK=32)

    __shared__ unsigned XL[2][16][RS];   // [buf][t-pair][row] w*X bf16x2
    __shared__ unsigned BL[2][16][RS];
    __shared__ float    WT[HGRP][TB];

    const int gid  = blockIdx.x;
    const int blk  = gid % NBLK;
    const int hg   = (gid / NBLK) & 3;
    const int b    = gid / (4 * NBLK);
    const int tid  = threadIdx.x;
    const int w    = tid >> 6;
    const int lane = tid & 63;
    const int hloc = w >> 1;
    const int nh   = w & 1;
    const int h    = hg * HGRP + hloc;
    const int t0   = blk * TB;

    // ---- per-wave scan of A column h ----
    float c[Q];
    {
        const size_t abase = ((size_t)(b * SEQ + t0 + lane * Q)) * NH + h;
        float run = 0.f;
        #pragma unroll
        for (int k = 0; k < Q; ++k) { run += Ag[abase + (size_t)k * NH]; c[k] = run; }
    }
    float tsum = c[Q - 1], s = tsum;
    #pragma unroll
    for (int d = 1; d < 64; d <<= 1) {
        float o = __shfl_up(s, d, 64);
        if (lane >= d) s += o;
    }
    const float total = __shfl(s, 63, 64);
    const float excl  = s - tsum;
    if (nh == 0) {
        #pragma unroll
        for (int k = 0; k < Q; ++k)
            WT[hloc][lane * Q + k] = __expf(total - (excl + c[k]));
        if (lane == 63) blockA[(size_t)(b * NH + h) * NBLK + blk] = total;
    }

    f32x4 acc[4][2];
    #pragma unroll
    for (int mi = 0; mi < 4; ++mi)
        #pragma unroll
        for (int ni = 0; ni < 2; ++ni) acc[mi][ni] = (f32x4){0.f, 0.f, 0.f, 0.f};

    const int hl = lane >> 4;
    const int p4 = (lane & 15) * 4;
    const size_t gbase = (size_t)(b * SEQ + t0) * ROWF + hg * (HGRP * DP) + hl * DP + p4;

    auto issue = [&](int k, float4* lx, float4* lb) {
        if (k >= NKT) return;
        const size_t tb = gbase + (size_t)(k * KT + w * 4) * ROWF;
        #pragma unroll
        for (int i = 0; i < 4; ++i) {
            lx[i] = *(const float4*)(Xg + tb + (size_t)i * ROWF);
            lb[i] = *(const float4*)(Bg + tb + (size_t)i * ROWF);
        }
    };
    auto cwrite = [&](int k, int buf, const float4* lx, const float4* lb) {
        const int tIn = k * KT + w * 4;
        #pragma unroll
        for (int q = 0; q < 2; ++q) {
            const float w0 = WT[hl][tIn + 2 * q];
            const float w1 = WT[hl][tIn + 2 * q + 1];
            const int   tp = w * 2 + q;
            const float* x0 = (const float*)&lx[2 * q];
            const float* x1 = (const float*)&lx[2 * q + 1];
            const float* b0 = (const float*)&lb[2 * q];
            const float* b1 = (const float*)&lb[2 * q + 1];
            uint4 xv, bv;
            xv.x = pk2(x0[0] * w0, x1[0] * w1);
            xv.y = pk2(x0[1] * w0, x1[1] * w1);
            xv.z = pk2(x0[2] * w0, x1[2] * w1);
            xv.w = pk2(x0[3] * w0, x1[3] * w1);
            bv.x = pk2(b0[0], b1[0]);
            bv.y = pk2(b0[1], b1[1]);
            bv.z = pk2(b0[2], b1[2]);
            bv.w = pk2(b0[3], b1[3]);
            *(uint4*)&XL[buf][tp][hl * 64 + p4] = xv;   // one ds_write_b128
            *(uint4*)&BL[buf][tp][hl * 64 + p4] = bv;
        }
    };
    auto compute = [&](int buf) {
        const int r  = lane & 15;
        const int kg = lane >> 4;
        uint4 af[4], bf[2];
        #pragma unroll
        for (int mi = 0; mi < 4; ++mi) {
            const int row = hloc * 64 + mi * 16 + r;
            af[mi].x = XL[buf][kg * 4 + 0][row];
            af[mi].y = XL[buf][kg * 4 + 1][row];
            af[mi].z = XL[buf][kg * 4 + 2][row];
            af[mi].w = XL[buf][kg * 4 + 3][row];
        }
        #pragma unroll
        for (int ni = 0; ni < 2; ++ni) {
            const int row = hloc * 64 + nh * 32 + ni * 16 + r;
            bf[ni].x = BL[buf][kg * 4 + 0][row];
            bf[ni].y = BL[buf][kg * 4 + 1][row];
            bf[ni].z = BL[buf][kg * 4 + 2][row];
            bf[ni].w = BL[buf][kg * 4 + 3][row];
        }
        #pragma unroll
        for (int mi = 0; mi < 4; ++mi) {
            const bf16x8 a = __builtin_bit_cast(bf16x8, af[mi]);
            #pragma unroll
            for (int ni = 0; ni < 2; ++ni) {
                const bf16x8 bb = __builtin_bit_cast(bf16x8, bf[ni]);
                acc[mi][ni] = __builtin_amdgcn_mfma_f32_16x16x32_bf16(
                                  a, bb, acc[mi][ni], 0, 0, 0);
            }
        }
    };

    #define PHASE_BAR() do { \
        asm volatile("s_waitcnt lgkmcnt(0)" ::: "memory"); \
        __builtin_amdgcn_s_barrier(); \
        __builtin_amdgcn_sched_barrier(0); } while (0)

    if constexpr (NBLK == 32) {
        // ---- 3-deep fully-unrolled pipeline (NKT == 8) ----
        float4 s0x[4], s0b[4], s1x[4], s1b[4], s2x[4], s2b[4];
        issue(0, s0x, s0b);
        issue(1, s1x, s1b);
        issue(2, s2x, s2b);
        __syncthreads();                       // WT visible

        cwrite(0, 0, s0x, s0b); issue(3, s0x, s0b); PHASE_BAR();
        cwrite(1, 1, s1x, s1b); issue(4, s1x, s1b); compute(0); PHASE_BAR();  // t0
        cwrite(2, 0, s2x, s2b); issue(5, s2x, s2b); compute(1); PHASE_BAR();  // t1
        cwrite(3, 1, s0x, s0b); issue(6, s0x, s0b); compute(0); PHASE_BAR();  // t2
        cwrite(4, 0, s1x, s1b); issue(7, s1x, s1b); compute(1); PHASE_BAR();  // t3
        cwrite(5, 1, s2x, s2b);                     compute(0); PHASE_BAR();  // t4
        cwrite(6, 0, s0x, s0b);                     compute(1); PHASE_BAR();  // t5
        cwrite(7, 1, s1x, s1b);                     compute(0); PHASE_BAR();  // t6
        compute(1);                                                           // t7
    } else {
        // ---- generic 2-deep loop (r19 structure) for NBLK==16 fallback ----
        float4 sx0[4], sb0[4], sx1[4], sb1[4];
        issue(0, sx0, sb0);
        issue(1, sx1, sb1);
        __syncthreads();
        cwrite(0, 0, sx0, sb0); issue(2, sx0, sb0); PHASE_BAR();
        #pragma unroll 1
        for (int k = 0; k < NKT; k += 2) {
            if (k + 1 < NKT) { cwrite(k + 1, 1, sx1, sb1); issue(k + 3, sx1, sb1); }
            compute(0); PHASE_BAR();
            if (k + 2 < NKT) { cwrite(k + 2, 0, sx0, sb0); issue(k + 4, sx0, sb0); }
            if (k + 1 < NKT) compute(1);
            PHASE_BAR();
        }
    }
    #undef PHASE_BAR

    // ---- epilogue: C/D layout (m89): col = lane&15, row = (lane>>4)*4 + reg ----
    float* dst = part + ((size_t)(b * NH + h) * NBLK + blk) * 4096;
    {
        const int r  = lane & 15;
        const int cg = lane >> 4;
        #pragma unroll
        for (int mi = 0; mi < 4; ++mi)
            #pragma unroll
            for (int ni = 0; ni < 2; ++ni)
                #pragma unroll
                for (int rr = 0; rr < 4; ++rr)
                    dst[(mi * 16 + cg * 4 + rr) * 64 + nh * 32 + ni * 16 + r] =
                        acc[mi][ni][rr];
    }
}

// ---------------------------------------------------------------------------
__global__ void k_scales(const float* __restrict__ blockA, float* __restrict__ scale,
                         int nblk)
{
    const int bh = blockIdx.x * blockDim.x + threadIdx.x;
    if (bh < BATCH * NH) {
        float run = 0.f;
        for (int c2 = nblk - 1; c2 >= 0; --c2) {
            scale[bh * nblk + c2] = __expf(run);
            run += blockA[bh * nblk + c2];
        }
    }
}

// ---------------------------------------------------------------------------
__global__ __launch_bounds__(256)
void k_combine(const float* __restrict__ part, const float* __restrict__ scale,
               float* __restrict__ out, int nblk)
{
    const int idx = blockIdx.x * 256 + threadIdx.x;
    const int bh  = idx >> 12;
    const int e   = idx & 4095;
    float r = 0.f;
    for (int q = 0; q < nblk; ++q)
        r += scale[bh * nblk + q] * part[((size_t)bh * nblk + q) * 4096 + e];
    out[idx] = r;
}

// ---------------------------------------------------------------------------
extern "C" void kernel_launch(void* const* d_in, const int* in_sizes, int n_in,
                              void* d_out, int out_size, void* d_ws, size_t ws_size,
                              hipStream_t stream)
{
    const float* X = (const float*)d_in[0];
    const float* A = (const float*)d_in[1];
    const float* B = (const float*)d_in[2];
    float* out     = (float*)d_out;

    const size_t need32 = ((size_t)BATCH * NH * 32 * 4096 + 2ull * BATCH * NH * 32) * 4;
    const int nblk = (ws_size >= need32) ? 32 : 16;

    float* part   = (float*)d_ws;
    float* blockA = part + (size_t)BATCH * NH * nblk * 4096;
    float* scale  = blockA + (size_t)BATCH * NH * nblk;

    if (nblk == 32)
        hipLaunchKernelGGL((k_partial<32>), dim3(BATCH * 4 * 32), dim3(NTHR), 0, stream,
                           X, A, B, part, blockA);
    else
        hipLaunchKernelGGL((k_partial<16>), dim3(BATCH * 4 * 16), dim3(NTHR), 0, stream,
                           X, A, B, part, blockA);

    hipLaunchKernelGGL(k_scales, dim3(1), dim3(128), 0, stream, blockA, scale, nblk);
    hipLaunchKernelGGL(k_combine, dim3((BATCH * NH * 4096) / 256), dim3(256), 0, stream,
                       part, scale, out, nblk);
}